// Round 10
// baseline (824.401 us; speedup 1.0000x reference)
//
#include <hip/hip_runtime.h>
#include <cfloat>

// Problem constants
#define T_TOTAL 32768   // 32*32*32 spatial positions
#define DIM 64          // embedding dim
#define KCODES 1024     // num embeddings

// ABLATION ROUND: three main-kernel dispatches.
//   1) vq_ablate_storeonly x5 iters — exact store pattern, zero values, no compute.
//   2) vq_ablate_nostore   x3 iters — full compute, all global stores sunk (asm).
//   3) vq_main_kernel      x1       — the real R7-structure kernel (runs last,
//      produces the exact final outputs; correctness unchanged).
// Top-5 rocprof rows then give per-variant dur + counters -> decisive split of
// the ~147us into store-path vs compute/latency cost.

static constexpr long long OFF_Q    = 0;
static constexpr long long OFF_LOSS = 2097152;
static constexpr long long OFF_PERP = 2097153;
static constexpr long long OFF_ENC  = 2097154;            // enc+2 is 16B aligned
static constexpr long long OFF_DIST = 2097154LL + 33554432LL;

// ws layout: [0,4096) int counts[1024]; [4096,8192) float ww[1024];
//            [8192,8196) float lossSum; [12288, 12288+256K) float WT[64][1024]

#define AS1 __attribute__((address_space(1)))
#define AS3 __attribute__((address_space(3)))

typedef float __attribute__((ext_vector_type(2))) f32x2;
typedef float __attribute__((ext_vector_type(4))) f32x4;

__device__ __forceinline__ void ntstore2(float* p, float a, float b) {
    f32x2 v = {a, b};
    __builtin_nontemporal_store(v, (f32x2*)p);
}
__device__ __forceinline__ void ntstore4z(float* p) {
    f32x4 v = {0.f, 0.f, 0.f, 0.f};
    __builtin_nontemporal_store(v, (f32x4*)p);
}
__device__ __forceinline__ void ntstore4(float* p, float a, float b, float c, float d) {
    f32x4 v = {a, b, c, d};
    __builtin_nontemporal_store(v, (f32x4*)p);
}

__device__ __forceinline__ void gld16(const float* g, float* l) {
    __builtin_amdgcn_global_load_lds((const AS1 unsigned int*)g,
                                     (AS3 unsigned int*)l, 16, 0, 0);
}

#define PHASE_SYNC(N) do {                                        \
    asm volatile("s_waitcnt vmcnt(" #N ")" ::: "memory");         \
    __builtin_amdgcn_s_barrier();                                 \
    __builtin_amdgcn_sched_barrier(0);                            \
} while (0)

#define SINK4(a,b,c,d) asm volatile("" :: "v"(a), "v"(b), "v"(c), "v"(d))

// ---------------------------------------------------------------------------
__global__ __launch_bounds__(256) void vq_prep_kernel(const float* __restrict__ W,
                                                      float* __restrict__ ww,
                                                      float* __restrict__ WT,
                                                      float* __restrict__ out,
                                                      int* __restrict__ counts,
                                                      float* __restrict__ lossSum) {
    const int tid = threadIdx.x;
    const int b   = blockIdx.x;
    if (b < 256) {
        const int lane = tid & 63;
        const int code = b * 4 + (tid >> 6);
        float v = W[code * DIM + lane];
        float s = v * v;
        #pragma unroll
        for (int off = 32; off > 0; off >>= 1)
            s += __shfl_down(s, off, 64);
        if (lane == 0) ww[code] = s;
    } else if (b < 320) {
        const int n = b - 256;
        #pragma unroll
        for (int i = 0; i < 4; ++i) {
            int k = i * 256 + tid;
            WT[n * KCODES + k] = W[k * DIM + n];
        }
    } else if (b < 384) {
        float* __restrict__ enc = out + OFF_ENC;
        const int r0 = (b - 320) * 512 + tid * 2;
        const long long rb = (long long)r0 * KCODES;
        ntstore2(&enc[rb], 0.f, 0.f);
        ntstore2(&enc[rb + 1022], 0.f, 0.f);
        ntstore2(&enc[rb + 1024], 0.f, 0.f);
        ntstore2(&enc[rb + 1024 + 1022], 0.f, 0.f);
    } else {
        #pragma unroll
        for (int i = 0; i < 4; ++i) counts[i * 256 + tid] = 0;
        if (tid == 0) lossSum[0] = 0.f;
    }
}

// ---------------------------------------------------------------------------
// ABLATION A: store-only. Exact addresses/widths/sync cadence of the main
// kernel's stores, values all zero, no LDS/GEMM. 5 iterations.
__global__ __launch_bounds__(256, 2) void vq_ablate_storeonly(float* __restrict__ out) {
    const int tid = threadIdx.x;
    const int tx  = tid & 31;
    const int ty  = tid >> 5;
    const int t0  = blockIdx.x * 64;
    const long long base = (long long)(t0 >> 10) * 65536 + (long long)(t0 & 1023);
    float* __restrict__ distOut = out + OFF_DIST;
    float* __restrict__ enc     = out + OFF_ENC;
    const int tcl = (tid < 255 ? tid : 254) * 4;

    for (int iter = 0; iter < 5; ++iter) {
        for (int p = 0; p < 16; ++p) {
            const int c = p >> 3;
            const int q = p & 7;
            {   // enc zero-fill, same as main
                float* pz = enc + (long long)(t0 + p * 4) * KCODES + 2;
                ntstore4z(pz + tcl);
                ntstore4z(pz + 1024 + tcl);
                ntstore4z(pz + 2048 + tcl);
                ntstore4z(pz + 3072 + tcl);
            }
            if (q == 7) {   // dist stores, same addresses, zero values
                const int kb = c * 512 + tx * 4;
                #pragma unroll
                for (int r = 0; r < 8; ++r) {
                    const int row = (r >> 2) * 32 + ty * 4 + (r & 3);
                    const long long ro = (long long)(t0 + row) * KCODES + kb;
                    #pragma unroll
                    for (int qq = 0; qq < 4; ++qq) {
                        ntstore2(&distOut[ro + qq * 128],     0.f, 0.f);
                        ntstore2(&distOut[ro + qq * 128 + 2], 0.f, 0.f);
                    }
                }
            }
            if (q == 7) PHASE_SYNC(63);
            else        PHASE_SYNC(4);
        }
        // epilogue Q stores (zeros; overwritten by the real main later)
        #pragma unroll
        for (int i = 0; i < 4; ++i) {
            int e2  = i * 256 + tid;
            int n   = e2 >> 4;
            int tl0 = (e2 & 15) * 4;
            ntstore4(&out[OFF_Q + base + (long long)n * 1024 + tl0], 0.f, 0.f, 0.f, 0.f);
        }
        __syncthreads();
    }
}

// ---------------------------------------------------------------------------
// ABLATION B: no-store. Full staging + GEMM + argmin; every global store
// replaced by an asm value-sink (anti-DCE). PHASE_SYNC(0) everywhere (without
// stores, vmcnt(4) would no-op and race the wS double buffer). 3 iterations.
__global__ __launch_bounds__(256, 2) void vq_ablate_nostore(const float* __restrict__ lat,
                                                            const float* __restrict__ ww,
                                                            const float* __restrict__ WT) {
    __shared__ float xT[64 * 64];
    __shared__ float wS[2][8 * 512];
    __shared__ float wwS[KCODES];
    __shared__ float xx[64];
    __shared__ int   selIdx[64];

    const int tid = threadIdx.x;
    const int tx  = tid & 31;
    const int ty  = tid >> 5;
    const int t0  = blockIdx.x * 64;
    const long long base = (long long)(t0 >> 10) * 65536 + (long long)(t0 & 1023);
    const int wbase = (tid & 192) * 4;

    for (int iter = 0; iter < 3; ++iter) {
        #pragma unroll
        for (int i = 0; i < 4; ++i) {
            const int e = i * 256 + tid;
            gld16(&lat[base + (long long)(e >> 4) * 1024 + (e & 15) * 4],
                  &xT[i * 1024 + wbase]);
        }
        #pragma unroll
        for (int i = 0; i < 4; ++i) {
            const int e = i * 256 + tid;
            gld16(&WT[(e >> 7) * KCODES + (e & 127) * 4],
                  &wS[0][i * 1024 + wbase]);
        }
        *(float4*)&wwS[tid * 4] = *(const float4*)&ww[tid * 4];
        __syncthreads();

        if (tid < 64) {
            float s = 0.f;
            #pragma unroll 8
            for (int n = 0; n < 64; ++n) {
                float v = xT[n * 64 + tid];
                s = fmaf(v, v, s);
            }
            xx[tid] = s;
        }

        float minV[8];
        int   minI[8];
        #pragma unroll
        for (int r = 0; r < 8; ++r) { minV[r] = FLT_MAX; minI[r] = 0; }
        float acc[8][16];

        for (int p = 0; p < 16; ++p) {
            const int c   = p >> 3;
            const int q   = p & 7;
            const int buf = p & 1;
            if (p < 15) {
                const int pn = p + 1;
                const float* srcb = WT + (pn & 7) * (8 * KCODES) + (pn >> 3) * 512;
                float* dstb = &wS[pn & 1][0];
                #pragma unroll
                for (int i = 0; i < 4; ++i) {
                    const int e = i * 256 + tid;
                    gld16(&srcb[(e >> 7) * KCODES + (e & 127) * 4],
                          &dstb[i * 1024 + wbase]);
                }
            }
            asm volatile("" ::: "memory");

            if (q == 0) {
                #pragma unroll
                for (int r = 0; r < 8; ++r)
                    #pragma unroll
                    for (int k = 0; k < 16; ++k) acc[r][k] = 0.f;
            }

            #pragma unroll 2
            for (int nn = 0; nn < 8; ++nn) {
                const float* xrow = &xT[(q * 8 + nn) * 64];
                const float* wrow = &wS[buf][nn * 512];
                float4 a0 = *(const float4*)&xrow[ty * 4];
                float4 a1 = *(const float4*)&xrow[32 + ty * 4];
                float4 b0 = *(const float4*)&wrow[tx * 4];
                float4 b1 = *(const float4*)&wrow[128 + tx * 4];
                float4 b2 = *(const float4*)&wrow[256 + tx * 4];
                float4 b3 = *(const float4*)&wrow[384 + tx * 4];
                float ar[8]  = {a0.x, a0.y, a0.z, a0.w, a1.x, a1.y, a1.z, a1.w};
                float br[16] = {b0.x, b0.y, b0.z, b0.w, b1.x, b1.y, b1.z, b1.w,
                                b2.x, b2.y, b2.z, b2.w, b3.x, b3.y, b3.z, b3.w};
                #pragma unroll
                for (int r = 0; r < 8; ++r)
                    #pragma unroll
                    for (int k = 0; k < 16; ++k)
                        acc[r][k] = fmaf(ar[r], br[k], acc[r][k]);
            }

            if (q == 7) {
                const int kb = c * 512 + tx * 4;
                float wr[16];
                #pragma unroll
                for (int qq = 0; qq < 4; ++qq) {
                    float4 w4 = *(const float4*)&wwS[kb + qq * 128];
                    wr[qq*4+0] = w4.x; wr[qq*4+1] = w4.y; wr[qq*4+2] = w4.z; wr[qq*4+3] = w4.w;
                }
                #pragma unroll
                for (int r = 0; r < 8; ++r) {
                    const int row = (r >> 2) * 32 + ty * 4 + (r & 3);
                    const float xxr = xx[row];
                    #pragma unroll
                    for (int qq = 0; qq < 4; ++qq) {
                        float d0 = (xxr + wr[qq*4+0]) - 2.f * acc[r][qq*4+0];
                        float d1 = (xxr + wr[qq*4+1]) - 2.f * acc[r][qq*4+1];
                        float d2 = (xxr + wr[qq*4+2]) - 2.f * acc[r][qq*4+2];
                        float d3 = (xxr + wr[qq*4+3]) - 2.f * acc[r][qq*4+3];
                        const int k0 = kb + qq * 128;
                        if (d0 < minV[r]) { minV[r] = d0; minI[r] = k0;     }
                        if (d1 < minV[r]) { minV[r] = d1; minI[r] = k0 + 1; }
                        if (d2 < minV[r]) { minV[r] = d2; minI[r] = k0 + 2; }
                        if (d3 < minV[r]) { minV[r] = d3; minI[r] = k0 + 3; }
                        SINK4(d0, d1, d2, d3);   // keep dist computation live, no store
                    }
                }
            }
            PHASE_SYNC(0);   // no stores outstanding: plain load-drain barrier
        }

        // argmin reduction (compute kept; no atomics, no global writes)
        float* wSf  = &wS[0][0];
        float* redV = wSf;
        int*   redI = (int*)(wSf + 64 * 33);
        #pragma unroll
        for (int r = 0; r < 8; ++r) {
            const int row = (r >> 2) * 32 + ty * 4 + (r & 3);
            redV[row * 33 + tx] = minV[r];
            redI[row * 33 + tx] = minI[r];
        }
        __syncthreads();
        if (tid < 64) {
            float best = redV[tid * 33];
            int   bi   = redI[tid * 33];
            #pragma unroll
            for (int s = 1; s < 32; ++s) {
                float v  = redV[tid * 33 + s];
                int   i2 = redI[tid * 33 + s];
                if (v < best || (v == best && i2 < bi)) { best = v; bi = i2; }
            }
            selIdx[tid] = bi;
            asm volatile("" :: "v"(best), "v"(bi));
        }
        __syncthreads();
    }
}

// ---------------------------------------------------------------------------
// The real main kernel — byte-identical to Round 7 (session best).
__global__ __launch_bounds__(256, 2) void vq_main_kernel(const float* __restrict__ lat,
                                                         const float* __restrict__ W,
                                                         const float* __restrict__ ww,
                                                         const float* __restrict__ WT,
                                                         float* __restrict__ out,
                                                         int* __restrict__ counts,
                                                         float* __restrict__ lossSum) {
    __shared__ float xT[64 * 64];
    __shared__ float wS[2][8 * 512];
    __shared__ float wwS[KCODES];
    __shared__ float xx[64];
    __shared__ int   selIdx[64];

    const int tid = threadIdx.x;
    const int tx  = tid & 31;
    const int ty  = tid >> 5;
    const int t0  = blockIdx.x * 64;
    const long long base = (long long)(t0 >> 10) * 65536 + (long long)(t0 & 1023);
    const int wbase = (tid & 192) * 4;

    #pragma unroll
    for (int i = 0; i < 4; ++i) {
        const int e = i * 256 + tid;
        gld16(&lat[base + (long long)(e >> 4) * 1024 + (e & 15) * 4],
              &xT[i * 1024 + wbase]);
    }
    #pragma unroll
    for (int i = 0; i < 4; ++i) {
        const int e = i * 256 + tid;
        gld16(&WT[(e >> 7) * KCODES + (e & 127) * 4],
              &wS[0][i * 1024 + wbase]);
    }
    *(float4*)&wwS[tid * 4] = *(const float4*)&ww[tid * 4];
    __syncthreads();

    if (tid < 64) {
        float s = 0.f;
        #pragma unroll 8
        for (int n = 0; n < 64; ++n) {
            float v = xT[n * 64 + tid];
            s = fmaf(v, v, s);
        }
        xx[tid] = s;
    }

    float minV[8];
    int   minI[8];
    #pragma unroll
    for (int r = 0; r < 8; ++r) { minV[r] = FLT_MAX; minI[r] = 0; }

    float acc[8][16];
    float* __restrict__ distOut = out + OFF_DIST;
    float* __restrict__ enc     = out + OFF_ENC;
    const int tcl = (tid < 255 ? tid : 254) * 4;

    for (int p = 0; p < 16; ++p) {
        const int c   = p >> 3;
        const int q   = p & 7;
        const int buf = p & 1;

        if (p < 15) {
            const int pn = p + 1;
            const float* srcb = WT + (pn & 7) * (8 * KCODES) + (pn >> 3) * 512;
            float* dstb = &wS[pn & 1][0];
            #pragma unroll
            for (int i = 0; i < 4; ++i) {
                const int e = i * 256 + tid;
                gld16(&srcb[(e >> 7) * KCODES + (e & 127) * 4],
                      &dstb[i * 1024 + wbase]);
            }
        }
        asm volatile("" ::: "memory");

        {
            float* pz = enc + (long long)(t0 + p * 4) * KCODES + 2;
            ntstore4z(pz + tcl);
            ntstore4z(pz + 1024 + tcl);
            ntstore4z(pz + 2048 + tcl);
            ntstore4z(pz + 3072 + tcl);
        }

        if (q == 0) {
            #pragma unroll
            for (int r = 0; r < 8; ++r)
                #pragma unroll
                for (int k = 0; k < 16; ++k) acc[r][k] = 0.f;
        }

        #pragma unroll 2
        for (int nn = 0; nn < 8; ++nn) {
            const float* xrow = &xT[(q * 8 + nn) * 64];
            const float* wrow = &wS[buf][nn * 512];
            float4 a0 = *(const float4*)&xrow[ty * 4];
            float4 a1 = *(const float4*)&xrow[32 + ty * 4];
            float4 b0 = *(const float4*)&wrow[tx * 4];
            float4 b1 = *(const float4*)&wrow[128 + tx * 4];
            float4 b2 = *(const float4*)&wrow[256 + tx * 4];
            float4 b3 = *(const float4*)&wrow[384 + tx * 4];
            float ar[8]  = {a0.x, a0.y, a0.z, a0.w, a1.x, a1.y, a1.z, a1.w};
            float br[16] = {b0.x, b0.y, b0.z, b0.w, b1.x, b1.y, b1.z, b1.w,
                            b2.x, b2.y, b2.z, b2.w, b3.x, b3.y, b3.z, b3.w};
            #pragma unroll
            for (int r = 0; r < 8; ++r)
                #pragma unroll
                for (int k = 0; k < 16; ++k)
                    acc[r][k] = fmaf(ar[r], br[k], acc[r][k]);
        }

        if (q == 7) {
            const int kb = c * 512 + tx * 4;
            float wr[16];
            #pragma unroll
            for (int qq = 0; qq < 4; ++qq) {
                float4 w4 = *(const float4*)&wwS[kb + qq * 128];
                wr[qq*4+0] = w4.x; wr[qq*4+1] = w4.y; wr[qq*4+2] = w4.z; wr[qq*4+3] = w4.w;
            }
            #pragma unroll
            for (int r = 0; r < 8; ++r) {
                const int row = (r >> 2) * 32 + ty * 4 + (r & 3);
                const float xxr = xx[row];
                const long long ro = (long long)(t0 + row) * KCODES + kb;
                #pragma unroll
                for (int qq = 0; qq < 4; ++qq) {
                    float d0 = (xxr + wr[qq*4+0]) - 2.f * acc[r][qq*4+0];
                    float d1 = (xxr + wr[qq*4+1]) - 2.f * acc[r][qq*4+1];
                    float d2 = (xxr + wr[qq*4+2]) - 2.f * acc[r][qq*4+2];
                    float d3 = (xxr + wr[qq*4+3]) - 2.f * acc[r][qq*4+3];
                    const int k0 = kb + qq * 128;
                    if (d0 < minV[r]) { minV[r] = d0; minI[r] = k0;     }
                    if (d1 < minV[r]) { minV[r] = d1; minI[r] = k0 + 1; }
                    if (d2 < minV[r]) { minV[r] = d2; minI[r] = k0 + 2; }
                    if (d3 < minV[r]) { minV[r] = d3; minI[r] = k0 + 3; }
                    ntstore2(&distOut[ro + qq * 128],     d0, d1);
                    ntstore2(&distOut[ro + qq * 128 + 2], d2, d3);
                }
            }
        }

        if (q == 7) PHASE_SYNC(63);
        else        PHASE_SYNC(4);
    }

    float* wSf  = &wS[0][0];
    float* redV = wSf;
    int*   redI = (int*)(wSf + 64 * 33);
    #pragma unroll
    for (int r = 0; r < 8; ++r) {
        const int row = (r >> 2) * 32 + ty * 4 + (r & 3);
        redV[row * 33 + tx] = minV[r];
        redI[row * 33 + tx] = minI[r];
    }
    __syncthreads();
    if (tid < 64) {
        float best = redV[tid * 33];
        int   bi   = redI[tid * 33];
        #pragma unroll
        for (int s = 1; s < 32; ++s) {
            float v  = redV[tid * 33 + s];
            int   i2 = redI[tid * 33 + s];
            if (v < best || (v == best && i2 < bi)) { best = v; bi = i2; }
        }
        selIdx[tid] = bi;
        atomicAdd(&counts[bi], 1);
    }
    __syncthreads();

    float* qS = wSf;
    #pragma unroll
    for (int i = 0; i < 16; ++i) {
        int e   = i * 256 + tid;
        int row = e >> 6;
        int n   = e & 63;
        qS[row * 65 + n] = W[selIdx[row] * DIM + n];
    }
    __syncthreads();

    float ls = 0.f;
    #pragma unroll
    for (int i = 0; i < 4; ++i) {
        int e2  = i * 256 + tid;
        int n   = e2 >> 4;
        int tl0 = (e2 & 15) * 4;
        float q0 = qS[(tl0 + 0) * 65 + n];
        float q1 = qS[(tl0 + 1) * 65 + n];
        float q2 = qS[(tl0 + 2) * 65 + n];
        float q3 = qS[(tl0 + 3) * 65 + n];
        float x0 = xT[n * 64 + tl0 + 0];
        float x1 = xT[n * 64 + tl0 + 1];
        float x2 = xT[n * 64 + tl0 + 2];
        float x3 = xT[n * 64 + tl0 + 3];
        ntstore4(&out[OFF_Q + base + (long long)n * 1024 + tl0], q0, q1, q2, q3);
        float e0 = q0 - x0; ls = fmaf(e0, e0, ls);
        float e1 = q1 - x1; ls = fmaf(e1, e1, ls);
        float e2d = q2 - x2; ls = fmaf(e2d, e2d, ls);
        float e3 = q3 - x3; ls = fmaf(e3, e3, ls);
    }
    #pragma unroll
    for (int off = 32; off > 0; off >>= 1)
        ls += __shfl_down(ls, off, 64);
    if ((tid & 63) == 0) atomicAdd(lossSum, ls);

    if (tid < 64)
        enc[(long long)(t0 + tid) * KCODES + selIdx[tid]] = 1.f;
}

// ---------------------------------------------------------------------------
__global__ __launch_bounds__(1024) void vq_finalize_kernel(const int* __restrict__ counts,
                                                           const float* __restrict__ lossSum,
                                                           float* __restrict__ out) {
    __shared__ float red[16];
    const int tid = threadIdx.x;
    float p = (float)counts[tid] * (1.0f / 32768.0f);
    float term = p * logf(p + 1e-10f);
    #pragma unroll
    for (int off = 32; off > 0; off >>= 1)
        term += __shfl_down(term, off, 64);
    if ((tid & 63) == 0) red[tid >> 6] = term;
    __syncthreads();
    if (tid == 0) {
        float s = 0.f;
        #pragma unroll
        for (int i = 0; i < 16; ++i) s += red[i];
        out[OFF_PERP] = expf(-s);
        out[OFF_LOSS] = 0.25f * lossSum[0] * (1.0f / 2097152.0f);
    }
}

// ---------------------------------------------------------------------------
extern "C" void kernel_launch(void* const* d_in, const int* in_sizes, int n_in,
                              void* d_out, int out_size, void* d_ws, size_t ws_size,
                              hipStream_t stream) {
    (void)in_sizes; (void)n_in; (void)out_size; (void)ws_size;
    const float* lat = (const float*)d_in[0];   // [32,64,32,32]
    const float* W   = (const float*)d_in[1];   // [1024,64]
    float* out = (float*)d_out;

    int*   counts  = (int*)d_ws;
    float* ww      = (float*)((char*)d_ws + 4096);
    float* lossSum = (float*)((char*)d_ws + 8192);
    float* WT      = (float*)((char*)d_ws + 12288);   // 64x1024 fp32 = 256 KB

    vq_prep_kernel<<<385, 256, 0, stream>>>(W, ww, WT, out, counts, lossSum);
    // Ablation dispatches (results overwritten by the real main below):
    vq_ablate_storeonly<<<512, 256, 0, stream>>>(out);
    vq_ablate_nostore<<<512, 256, 0, stream>>>(lat, ww, WT);
    // The real kernel — runs last, produces the exact outputs:
    vq_main_kernel<<<512, 256, 0, stream>>>(lat, W, ww, WT, out, counts, lossSum);
    vq_finalize_kernel<<<1, 1024, 0, stream>>>(counts, lossSum, out);
}